// Round 14
// baseline (165.567 us; speedup 1.0000x reference)
//
#include <hip/hip_runtime.h>
#include <math.h>

#define B_   4
#define L_   1024
#define HID_ 768
#define NH_  12
#define D_   64
#define SCALE_ 0.125f
#define NEGV (-1e15f)

typedef __attribute__((ext_vector_type(4))) float  f32x4;
typedef __attribute__((ext_vector_type(8))) __bf16 bf16x8;
typedef __attribute__((ext_vector_type(8))) unsigned short ushort8v;
typedef __attribute__((ext_vector_type(4))) unsigned short ushort4v;

typedef const __attribute__((address_space(1))) unsigned int* gas1_t;
typedef __attribute__((address_space(3))) unsigned int*       las3_t;
#define GLDS16(g, l) __builtin_amdgcn_global_load_lds((gas1_t)(g), (las3_t)(l), 16, 0, 0)

static __device__ __forceinline__ unsigned short f2bf(float f) {
    unsigned int u = __builtin_bit_cast(unsigned int, f);
    u += 0x7fffu + ((u >> 16) & 1u);           // RNE
    return (unsigned short)(u >> 16);
}

// ---------------------------------------------------------------------------
// inp f32 -> bf16
// ---------------------------------------------------------------------------
__global__ __launch_bounds__(256) void convert_x_kernel(
    const float* __restrict__ in, unsigned short* __restrict__ out, int n4)
{
    int i = blockIdx.x * 256 + threadIdx.x;
    if (i < n4) {
        float4 v = reinterpret_cast<const float4*>(in)[i];
        ushort4v o;
        o.x = f2bf(v.x); o.y = f2bf(v.y); o.z = f2bf(v.z); o.w = f2bf(v.w);
        reinterpret_cast<ushort4v*>(out)[i] = o;
    }
}

// ---------------------------------------------------------------------------
// W f32 [768 in][768 out] -> Wt bf16 [768 out][768 in]. grid (12,12,6).
// ---------------------------------------------------------------------------
struct WArgs { const float* w[6]; unsigned short* wt[6]; };

__global__ __launch_bounds__(256) void transpose_w_kernel(WArgs a)
{
    const float* W = a.w[blockIdx.z];
    unsigned short* Wt = a.wt[blockIdx.z];
    __shared__ float t[64][65];
    const int tid = threadIdx.x;
    const int lr = tid >> 2, lc4 = (tid & 3) * 16;
    const int r0 = blockIdx.y * 64, c0 = blockIdx.x * 64;
#pragma unroll
    for (int j = 0; j < 4; ++j) {
        float4 v = *reinterpret_cast<const float4*>(&W[(size_t)(r0 + lr) * HID_ + c0 + lc4 + j * 4]);
        t[lr][lc4 + j * 4 + 0] = v.x;
        t[lr][lc4 + j * 4 + 1] = v.y;
        t[lr][lc4 + j * 4 + 2] = v.z;
        t[lr][lc4 + j * 4 + 3] = v.w;
    }
    __syncthreads();
    unsigned short tmp[16];
#pragma unroll
    for (int j = 0; j < 16; ++j) tmp[j] = f2bf(t[lc4 + j][lr]);
    unsigned short* dst = &Wt[(size_t)(c0 + lr) * HID_ + r0 + lc4];
    *reinterpret_cast<ushort8v*>(dst)     = *reinterpret_cast<ushort8v*>(&tmp[0]);
    *reinterpret_cast<ushort8v*>(dst + 8) = *reinterpret_cast<ushort8v*>(&tmp[8]);
}

// ---------------------------------------------------------------------------
// bf16 GEMM, BK=128 (6 iterations): C[4096,768] = A @ Wt^T + bias.
// Tile 64x128, 4 waves, 48 KB LDS, 3 blocks/CU. 16-chunk XOR swizzle.
// mode 0: f32 C ; mode 1: bf16 C ; mode 2: bf16 Vt[(b*768+n)*1024+l]
// ---------------------------------------------------------------------------
struct GemmJob {
    const unsigned short* A;
    const unsigned short* Wt;
    const float* bias;
    void* C;
    int mode;
    int relu;
    float scale;
};
struct GemmArgs { GemmJob j[3]; };

__global__ __launch_bounds__(256, 3) void gemm_bf16_kernel(GemmArgs args)
{
    const GemmJob jb = args.j[blockIdx.z];
    __shared__ unsigned short As[64 * 128];
    __shared__ unsigned short Bs[128 * 128];

    const int tid = threadIdx.x;
    const int w = tid >> 6, lane = tid & 63, g = lane >> 4, lq = lane & 15;
    const int m0 = blockIdx.x * 64, n0 = blockIdx.y * 128;

    f32x4 acc[4][2];
#pragma unroll
    for (int i = 0; i < 4; ++i)
#pragma unroll
        for (int j = 0; j < 2; ++j) acc[i][j] = (f32x4){0.f, 0.f, 0.f, 0.f};

    const int rr = tid >> 4;
    const int kq = ((tid & 15) ^ rr) * 8;
    const unsigned short* Abase = jb.A  + (size_t)m0 * HID_ + (size_t)rr * HID_ + kq;
    const unsigned short* Bbase = jb.Wt + (size_t)n0 * HID_ + (size_t)rr * HID_ + kq;
    char* AsB = (char*)As;
    char* BsB = (char*)Bs;
    const int wb = w * 1024;

    for (int k0 = 0; k0 < HID_; k0 += 128) {
        __syncthreads();
#pragma unroll
        for (int j = 0; j < 4; ++j)
            GLDS16(Abase + (size_t)(j * 16) * HID_ + k0, AsB + j * 4096 + wb);
#pragma unroll
        for (int j = 0; j < 8; ++j)
            GLDS16(Bbase + (size_t)(j * 16) * HID_ + k0, BsB + j * 4096 + wb);
        __syncthreads();

#pragma unroll
        for (int ks = 0; ks < 4; ++ks) {
            bf16x8 af[4], bf[2];
#pragma unroll
            for (int mi = 0; mi < 4; ++mi) {
                int row = mi * 16 + lq;
                int c = (ks * 4 + g) ^ lq;
                af[mi] = *reinterpret_cast<const bf16x8*>(AsB + row * 256 + c * 16);
            }
#pragma unroll
            for (int ni = 0; ni < 2; ++ni) {
                int row = w * 32 + ni * 16 + lq;
                int c = (ks * 4 + g) ^ lq;
                bf[ni] = *reinterpret_cast<const bf16x8*>(BsB + row * 256 + c * 16);
            }
            __builtin_amdgcn_s_setprio(1);
#pragma unroll
            for (int mi = 0; mi < 4; ++mi)
#pragma unroll
                for (int ni = 0; ni < 2; ++ni)
                    acc[mi][ni] = __builtin_amdgcn_mfma_f32_16x16x32_bf16(
                        af[mi], bf[ni], acc[mi][ni], 0, 0, 0);
            __builtin_amdgcn_s_setprio(0);
        }
    }

    float bcol[2];
#pragma unroll
    for (int ni = 0; ni < 2; ++ni) bcol[ni] = jb.bias[n0 + w * 32 + ni * 16 + lq];

#pragma unroll
    for (int mi = 0; mi < 4; ++mi) {
#pragma unroll
        for (int ni = 0; ni < 2; ++ni) {
            const int n = n0 + w * 32 + ni * 16 + lq;
            float v[4];
#pragma unroll
            for (int r = 0; r < 4; ++r) {
                float x = (acc[mi][ni][r] + bcol[ni]) * jb.scale;
                if (jb.relu) x = fmaxf(x, 0.f);
                v[r] = x;
            }
            const int mbase = m0 + mi * 16 + 4 * g;
            if (jb.mode == 0) {
                float* C = (float*)jb.C;
#pragma unroll
                for (int r = 0; r < 4; ++r)
                    C[(size_t)(mbase + r) * HID_ + n] = v[r];
            } else if (jb.mode == 1) {
                unsigned short* C = (unsigned short*)jb.C;
#pragma unroll
                for (int r = 0; r < 4; ++r)
                    C[(size_t)(mbase + r) * HID_ + n] = f2bf(v[r]);
            } else {
                unsigned short* C = (unsigned short*)jb.C;
                const int bb = mbase >> 10, ltok = mbase & 1023;
                ushort4v o;
                o.x = f2bf(v[0]); o.y = f2bf(v[1]); o.z = f2bf(v[2]); o.w = f2bf(v[3]);
                *reinterpret_cast<ushort4v*>(&C[(size_t)(bb * HID_ + n) * L_ + ltok]) = o;
            }
        }
    }
}

// ---------------------------------------------------------------------------
// Flash attention, bf16 MFMA, SWAPPED QK^T (unchanged from round 12/13).
// NOTE: this round the kernel is launched TWICE (idempotent) purely to
// measure t_attn = dur - 125.7us. No other changes.
// ---------------------------------------------------------------------------
__global__ __launch_bounds__(256, 3) void attn_mfma_kernel(
    const unsigned short* __restrict__ Qb, const unsigned short* __restrict__ Kb,
    const unsigned short* __restrict__ Vtb, const float* __restrict__ rel,
    const int* __restrict__ seq_len, const int* __restrict__ lex_num,
    unsigned short* __restrict__ ctx)
{
    const int qt = blockIdx.x, bh = blockIdx.y;
    const int b = bh / NH_, h = bh % NH_;
    const int q0 = qt * 64;
    const int sl = seq_len[b] + lex_num[0];
    const int nkt = (sl + 63) >> 6;

    __shared__ unsigned short Ks0[64 * 72], Ks1[64 * 72];
    __shared__ unsigned short Vs0[64 * 72], Vs1[64 * 72];
    __shared__ unsigned short Ps[64 * 72];

    const int tid = threadIdx.x;
    const int w = tid >> 6, lane = tid & 63, g = lane >> 4, lq = lane & 15;
    const int r0 = tid >> 3, cc0 = tid & 7;
    const int r1 = 32 + r0;

    const unsigned short* Kbase = Kb  + (size_t)(b * L_) * HID_ + h * D_;
    const unsigned short* Vbase = Vtb + (size_t)(b * HID_ + h * D_) * L_;
    const float* relbase = rel + (size_t)bh * (L_ * L_) + (size_t)(q0 + w * 16 + lq) * L_ + 4 * g;

    bf16x8 aq[2];
#pragma unroll
    for (int ks = 0; ks < 2; ++ks)
        aq[ks] = *reinterpret_cast<const bf16x8*>(
            &Qb[(size_t)(b * L_ + q0 + w * 16 + lq) * HID_ + h * D_ + ks * 32 + g * 8]);

    f32x4 acc[4];
#pragma unroll
    for (int i = 0; i < 4; ++i) acc[i] = (f32x4){0.f, 0.f, 0.f, 0.f};
    float m_r = -3e38f, l_r = 0.f;

    ushort8v kA0, kA1, vA0, vA1, kB0, kB1, vB0, vB1;
    f32x4 relA[4], relB[4];

    auto load_set = [&](int kt_, ushort8v& K0, ushort8v& K1, ushort8v& V0,
                        ushort8v& V1, f32x4 (&R)[4]) {
        const int k0 = kt_ * 64;
        K0 = *reinterpret_cast<const ushort8v*>(&Kbase[(size_t)(k0 + r0) * HID_ + cc0 * 8]);
        K1 = *reinterpret_cast<const ushort8v*>(&Kbase[(size_t)(k0 + r1) * HID_ + cc0 * 8]);
        V0 = *reinterpret_cast<const ushort8v*>(&Vbase[(size_t)r0 * L_ + k0 + cc0 * 8]);
        V1 = *reinterpret_cast<const ushort8v*>(&Vbase[(size_t)r1 * L_ + k0 + cc0 * 8]);
#pragma unroll
        for (int ni = 0; ni < 4; ++ni)
            R[ni] = *reinterpret_cast<const f32x4*>(&relbase[k0 + ni * 16]);
    };

    auto body = [&](int kt_, ushort8v& K0, ushort8v& K1, ushort8v& V0, ushort8v& V1,
                    f32x4 (&R)[4], unsigned short* KsC, unsigned short* VsC) {
        const int k0 = kt_ * 64;
        *reinterpret_cast<ushort8v*>(&KsC[r0 * 72 + cc0 * 8]) = K0;
        *reinterpret_cast<ushort8v*>(&KsC[r1 * 72 + cc0 * 8]) = K1;
        *reinterpret_cast<ushort8v*>(&VsC[r0 * 72 + cc0 * 8]) = V0;
        *reinterpret_cast<ushort8v*>(&VsC[r1 * 72 + cc0 * 8]) = V1;
        __syncthreads();

        {
            int tn = kt_ + 2; if (tn > nkt - 1) tn = nkt - 1;
            const int kn = tn * 64;
            K0 = *reinterpret_cast<const ushort8v*>(&Kbase[(size_t)(kn + r0) * HID_ + cc0 * 8]);
            K1 = *reinterpret_cast<const ushort8v*>(&Kbase[(size_t)(kn + r1) * HID_ + cc0 * 8]);
            V0 = *reinterpret_cast<const ushort8v*>(&Vbase[(size_t)r0 * L_ + kn + cc0 * 8]);
            V1 = *reinterpret_cast<const ushort8v*>(&Vbase[(size_t)r1 * L_ + kn + cc0 * 8]);
        }

        // S^T = K @ Q^T
        f32x4 s[4];
#pragma unroll
        for (int ni = 0; ni < 4; ++ni) s[ni] = (f32x4){0.f, 0.f, 0.f, 0.f};
        __builtin_amdgcn_s_setprio(1);
#pragma unroll
        for (int ks = 0; ks < 2; ++ks) {
#pragma unroll
            for (int ni = 0; ni < 4; ++ni) {
                bf16x8 bk = *reinterpret_cast<const bf16x8*>(
                    &KsC[(ni * 16 + lq) * 72 + ks * 32 + g * 8]);
                s[ni] = __builtin_amdgcn_mfma_f32_16x16x32_bf16(bk, aq[ks], s[ni], 0, 0, 0);
            }
        }
        __builtin_amdgcn_s_setprio(0);

        float sv[4][4];
#pragma unroll
        for (int ni = 0; ni < 4; ++ni) {
            const int colb = k0 + ni * 16 + 4 * g;
#pragma unroll
            for (int r = 0; r < 4; ++r)
                sv[ni][r] = (colb + r < sl) ? (s[ni][r] + R[ni][r]) : NEGV;
        }

        {
            int tn = kt_ + 2; if (tn > nkt - 1) tn = nkt - 1;
            const int kn = tn * 64;
#pragma unroll
            for (int ni = 0; ni < 4; ++ni)
                R[ni] = *reinterpret_cast<const f32x4*>(&relbase[kn + ni * 16]);
        }

        float rm = sv[0][0];
#pragma unroll
        for (int ni = 0; ni < 4; ++ni)
#pragma unroll
            for (int r = 0; r < 4; ++r) rm = fmaxf(rm, sv[ni][r]);
        rm = fmaxf(rm, __shfl_xor(rm, 16));
        rm = fmaxf(rm, __shfl_xor(rm, 32));
        const float mn = fmaxf(m_r, rm);
        const float sc = __expf(m_r - mn);
        float p[4][4];
        float rs = 0.f;
#pragma unroll
        for (int ni = 0; ni < 4; ++ni)
#pragma unroll
            for (int r = 0; r < 4; ++r) {
                p[ni][r] = __expf(sv[ni][r] - mn);
                rs += p[ni][r];
            }
        rs += __shfl_xor(rs, 16);
        rs += __shfl_xor(rs, 32);
        l_r = l_r * sc + rs;
        m_r = mn;
#pragma unroll
        for (int ni = 0; ni < 4; ++ni) acc[ni] *= sc;

#pragma unroll
        for (int ni = 0; ni < 4; ++ni) {
            ushort4v o;
            o.x = f2bf(p[ni][0]); o.y = f2bf(p[ni][1]);
            o.z = f2bf(p[ni][2]); o.w = f2bf(p[ni][3]);
            *reinterpret_cast<ushort4v*>(&Ps[(w * 16 + lq) * 72 + ni * 16 + 4 * g]) = o;
        }

        // O^T += V^T @ P^T
        __builtin_amdgcn_s_setprio(1);
#pragma unroll
        for (int ks = 0; ks < 2; ++ks) {
            bf16x8 ap = *reinterpret_cast<const bf16x8*>(
                &Ps[(w * 16 + lq) * 72 + ks * 32 + g * 8]);
#pragma unroll
            for (int ni = 0; ni < 4; ++ni) {
                bf16x8 bv = *reinterpret_cast<const bf16x8*>(
                    &VsC[(ni * 16 + lq) * 72 + ks * 32 + g * 8]);
                acc[ni] = __builtin_amdgcn_mfma_f32_16x16x32_bf16(bv, ap, acc[ni], 0, 0, 0);
            }
        }
        __builtin_amdgcn_s_setprio(0);
    };

    load_set(0, kA0, kA1, vA0, vA1, relA);
    load_set(nkt > 1 ? 1 : 0, kB0, kB1, vB0, vB1, relB);

    for (int kt = 0; kt < nkt; kt += 2) {
        body(kt, kA0, kA1, vA0, vA1, relA, Ks0, Vs0);
        if (kt + 1 < nkt)
            body(kt + 1, kB0, kB1, vB0, vB1, relB, Ks1, Vs1);
    }

    const float inv = 1.f / l_r;
    unsigned short* cbase = ctx + (size_t)(b * L_ + q0 + w * 16 + lq) * HID_ + h * D_;
#pragma unroll
    for (int ni = 0; ni < 4; ++ni) {
        ushort4v o;
        o.x = f2bf(acc[ni][0] * inv);
        o.y = f2bf(acc[ni][1] * inv);
        o.z = f2bf(acc[ni][2] * inv);
        o.w = f2bf(acc[ni][3] * inv);
        *reinterpret_cast<ushort4v*>(&cbase[ni * 16 + 4 * g]) = o;
    }
}

// ---------------------------------------------------------------------------
// LayerNorm(2*x) over rows of 768; out f32 or bf16.
// ---------------------------------------------------------------------------
__global__ __launch_bounds__(256) void ln2_kernel(
    const float* __restrict__ in, const float* __restrict__ g,
    const float* __restrict__ bta, void* __restrict__ out, int bf16out)
{
    const int row = blockIdx.x;
    const float* x = in + (size_t)row * HID_;
    const int tid = threadIdx.x;

    float vals[3];
    float s = 0.f, ss = 0.f;
#pragma unroll
    for (int j = 0; j < 3; ++j) {
        float t = 2.f * x[tid + j * 256];
        vals[j] = t;
        s += t;
        ss += t * t;
    }
#pragma unroll
    for (int m = 1; m < 64; m <<= 1) {
        s += __shfl_xor(s, m, 64);
        ss += __shfl_xor(ss, m, 64);
    }
    __shared__ float sb[4], ssb[4];
    if ((tid & 63) == 0) { sb[tid >> 6] = s; ssb[tid >> 6] = ss; }
    __syncthreads();
    s = sb[0] + sb[1] + sb[2] + sb[3];
    ss = ssb[0] + ssb[1] + ssb[2] + ssb[3];
    const float mean = s * (1.f / 768.f);
    float var = ss * (1.f / 768.f) - mean * mean;
    if (var < 0.f) var = 0.f;
    const float invs = rsqrtf(var + 1e-5f);
    if (bf16out) {
        unsigned short* o = (unsigned short*)out;
#pragma unroll
        for (int j = 0; j < 3; ++j) {
            int c = tid + j * 256;
            o[(size_t)row * HID_ + c] = f2bf((vals[j] - mean) * invs * g[c] + bta[c]);
        }
    } else {
        float* o = (float*)out;
#pragma unroll
        for (int j = 0; j < 3; ++j) {
            int c = tid + j * 256;
            o[(size_t)row * HID_ + c] = (vals[j] - mean) * invs * g[c] + bta[c];
        }
    }
}

// ---------------------------------------------------------------------------
extern "C" void kernel_launch(void* const* d_in, const int* in_sizes, int n_in,
                              void* d_out, int out_size, void* d_ws, size_t ws_size,
                              hipStream_t stream) {
    const float* inp     = (const float*)d_in[0];
    const int*   seq_len = (const int*)d_in[1];
    const int*   lex_num = (const int*)d_in[2];
    const float* rel     = (const float*)d_in[3];
    const float* Wq = (const float*)d_in[4];
    const float* bq = (const float*)d_in[5];
    const float* Wk = (const float*)d_in[6];
    const float* bk = (const float*)d_in[7];
    const float* Wv = (const float*)d_in[8];
    const float* bv = (const float*)d_in[9];
    const float* Wo = (const float*)d_in[10];
    const float* bo = (const float*)d_in[11];
    const float* W0 = (const float*)d_in[12];
    const float* b0 = (const float*)d_in[13];
    const float* W1 = (const float*)d_in[14];
    const float* b1 = (const float*)d_in[15];
    const float* ln_g = (const float*)d_in[16];
    const float* ln_b = (const float*)d_in[17];
    float* out = (float*)d_out;

    // ---- workspace carve (bytes) ----
    char* W = (char*)d_ws;
    const size_t WT_SZ = (size_t)HID_ * HID_ * 2;
    unsigned short* Wt[6];
    for (int i = 0; i < 6; ++i) Wt[i] = (unsigned short*)(W + i * WT_SZ);
    size_t off = 6 * WT_SZ;
    const size_t TOK_BF = (size_t)B_ * L_ * HID_ * 2;
    unsigned short* qb  = (unsigned short*)(W + off); off += TOK_BF;
    unsigned short* kb  = (unsigned short*)(W + off); off += TOK_BF;
    unsigned short* vtb = (unsigned short*)(W + off); off += TOK_BF;
    unsigned short* Eb  = (unsigned short*)(W + off); off += TOK_BF;
    float* Fbuf = (float*)(W + off);

    unsigned short* Xb   = Eb;
    unsigned short* ctxb = Eb;
    unsigned short* y2b  = vtb;
    unsigned short* hb   = qb;

    convert_x_kernel<<<dim3(3072), dim3(256), 0, stream>>>(inp, Xb, (B_ * L_ * HID_) / 4);

    {
        WArgs wa;
        const float* ws_[6] = {Wq, Wk, Wv, Wo, W0, W1};
        for (int i = 0; i < 6; ++i) { wa.w[i] = ws_[i]; wa.wt[i] = Wt[i]; }
        transpose_w_kernel<<<dim3(12, 12, 6), dim3(256), 0, stream>>>(wa);
    }

    {
        GemmArgs ga;
        ga.j[0] = {Xb, Wt[0], bq, (void*)qb,  1, 0, SCALE_};
        ga.j[1] = {Xb, Wt[1], bk, (void*)kb,  1, 0, 1.f};
        ga.j[2] = {Xb, Wt[2], bv, (void*)vtb, 2, 0, 1.f};
        gemm_bf16_kernel<<<dim3(64, 6, 3), dim3(256), 0, stream>>>(ga);
    }

    // MEASUREMENT ROUND: attention launched twice (idempotent, deterministic).
    // t_attn = dur_round14 - dur_round13 (125.7us). Remove duplicate next round.
    attn_mfma_kernel<<<dim3(16, 48), dim3(256), 0, stream>>>(
        qb, kb, vtb, rel, seq_len, lex_num, ctxb);
    attn_mfma_kernel<<<dim3(16, 48), dim3(256), 0, stream>>>(
        qb, kb, vtb, rel, seq_len, lex_num, ctxb);

    {
        GemmArgs ga;
        ga.j[0] = {ctxb, Wt[3], bo, (void*)Fbuf, 0, 0, 1.f};
        gemm_bf16_kernel<<<dim3(64, 6, 1), dim3(256), 0, stream>>>(ga);
    }
    ln2_kernel<<<dim3(4096), dim3(256), 0, stream>>>(Fbuf, ln_g, ln_b, (void*)y2b, 1);
    {
        GemmArgs ga;
        ga.j[0] = {y2b, Wt[4], b0, (void*)hb, 1, 1, 1.f};
        gemm_bf16_kernel<<<dim3(64, 6, 1), dim3(256), 0, stream>>>(ga);
    }
    {
        GemmArgs ga;
        ga.j[0] = {hb, Wt[5], b1, (void*)Fbuf, 0, 0, 1.f};
        gemm_bf16_kernel<<<dim3(64, 6, 1), dim3(256), 0, stream>>>(ga);
    }
    ln2_kernel<<<dim3(4096), dim3(256), 0, stream>>>(Fbuf, ln_g, ln_b, (void*)out, 0);
}

// Round 15
// 124.986 us; speedup vs baseline: 1.3247x; 1.3247x over previous
//
#include <hip/hip_runtime.h>
#include <math.h>

#define B_   4
#define L_   1024
#define HID_ 768
#define NH_  12
#define D_   64
#define SCALE_ 0.125f
#define NEGV (-1e15f)

typedef __attribute__((ext_vector_type(4))) float  f32x4;
typedef __attribute__((ext_vector_type(8))) __bf16 bf16x8;
typedef __attribute__((ext_vector_type(8))) unsigned short ushort8v;
typedef __attribute__((ext_vector_type(4))) unsigned short ushort4v;

typedef const __attribute__((address_space(1))) unsigned int* gas1_t;
typedef __attribute__((address_space(3))) unsigned int*       las3_t;
#define GLDS16(g, l) __builtin_amdgcn_global_load_lds((gas1_t)(g), (las3_t)(l), 16, 0, 0)

static __device__ __forceinline__ unsigned short f2bf(float f) {
    unsigned int u = __builtin_bit_cast(unsigned int, f);
    u += 0x7fffu + ((u >> 16) & 1u);           // RNE
    return (unsigned short)(u >> 16);
}

// ---------------------------------------------------------------------------
// inp f32 -> bf16
// ---------------------------------------------------------------------------
__global__ __launch_bounds__(256) void convert_x_kernel(
    const float* __restrict__ in, unsigned short* __restrict__ out, int n4)
{
    int i = blockIdx.x * 256 + threadIdx.x;
    if (i < n4) {
        float4 v = reinterpret_cast<const float4*>(in)[i];
        ushort4v o;
        o.x = f2bf(v.x); o.y = f2bf(v.y); o.z = f2bf(v.z); o.w = f2bf(v.w);
        reinterpret_cast<ushort4v*>(out)[i] = o;
    }
}

// ---------------------------------------------------------------------------
// W f32 [768 in][768 out] -> Wt bf16 [768 out][768 in]. grid (12,12,6).
// ---------------------------------------------------------------------------
struct WArgs { const float* w[6]; unsigned short* wt[6]; };

__global__ __launch_bounds__(256) void transpose_w_kernel(WArgs a)
{
    const float* W = a.w[blockIdx.z];
    unsigned short* Wt = a.wt[blockIdx.z];
    __shared__ float t[64][65];
    const int tid = threadIdx.x;
    const int lr = tid >> 2, lc4 = (tid & 3) * 16;
    const int r0 = blockIdx.y * 64, c0 = blockIdx.x * 64;
#pragma unroll
    for (int j = 0; j < 4; ++j) {
        float4 v = *reinterpret_cast<const float4*>(&W[(size_t)(r0 + lr) * HID_ + c0 + lc4 + j * 4]);
        t[lr][lc4 + j * 4 + 0] = v.x;
        t[lr][lc4 + j * 4 + 1] = v.y;
        t[lr][lc4 + j * 4 + 2] = v.z;
        t[lr][lc4 + j * 4 + 3] = v.w;
    }
    __syncthreads();
    unsigned short tmp[16];
#pragma unroll
    for (int j = 0; j < 16; ++j) tmp[j] = f2bf(t[lc4 + j][lr]);
    unsigned short* dst = &Wt[(size_t)(c0 + lr) * HID_ + r0 + lc4];
    *reinterpret_cast<ushort8v*>(dst)     = *reinterpret_cast<ushort8v*>(&tmp[0]);
    *reinterpret_cast<ushort8v*>(dst + 8) = *reinterpret_cast<ushort8v*>(&tmp[8]);
}

// ---------------------------------------------------------------------------
// bf16 GEMM, 64x64 tile, BK=128 (6 iterations), 32 KB LDS.
// Singles grid (64,12,1) = 768 blocks = 3 blocks/CU (was 1.5 at 64x128 —
// the R14 measurement showed the single-GEMM launches were occupancy-starved).
// 4 waves: wave w owns cols w*16..w*16+15, all 64 rows (4x1 frags).
// 16-chunk XOR swizzle identical to R13.
// mode 0: f32 C ; mode 1: bf16 C ; mode 2: bf16 Vt[(b*768+n)*1024+l]
// ---------------------------------------------------------------------------
struct GemmJob {
    const unsigned short* A;
    const unsigned short* Wt;
    const float* bias;
    void* C;
    int mode;
    int relu;
    float scale;
};
struct GemmArgs { GemmJob j[3]; };

__global__ __launch_bounds__(256, 3) void gemm_bf16_kernel(GemmArgs args)
{
    const GemmJob jb = args.j[blockIdx.z];
    __shared__ unsigned short As[64 * 128];    // 16 KB, chunk-XOR-swizzled
    __shared__ unsigned short Bs[64 * 128];    // 16 KB

    const int tid = threadIdx.x;
    const int w = tid >> 6, lane = tid & 63, g = lane >> 4, lq = lane & 15;
    const int m0 = blockIdx.x * 64, n0 = blockIdx.y * 64;

    f32x4 acc[4];
#pragma unroll
    for (int i = 0; i < 4; ++i) acc[i] = (f32x4){0.f, 0.f, 0.f, 0.f};

    // staging: call j, chunk c = j*256+tid; row = j*16+(tid>>4),
    // stored chunk = tid&15, source k-chunk = (tid&15)^(row&15)
    const int rr = tid >> 4;
    const int kq = ((tid & 15) ^ rr) * 8;
    const unsigned short* Abase = jb.A  + (size_t)(m0 + rr) * HID_ + kq;
    const unsigned short* Bbase = jb.Wt + (size_t)(n0 + rr) * HID_ + kq;
    char* AsB = (char*)As;
    char* BsB = (char*)Bs;
    const int wb = w * 1024;

    for (int k0 = 0; k0 < HID_; k0 += 128) {
        __syncthreads();
#pragma unroll
        for (int j = 0; j < 4; ++j)
            GLDS16(Abase + (size_t)(j * 16) * HID_ + k0, AsB + j * 4096 + wb);
#pragma unroll
        for (int j = 0; j < 4; ++j)
            GLDS16(Bbase + (size_t)(j * 16) * HID_ + k0, BsB + j * 4096 + wb);
        __syncthreads();

#pragma unroll
        for (int ks = 0; ks < 4; ++ks) {
            bf16x8 af[4], bfr;
            const int c = (ks * 4 + g) ^ lq;
#pragma unroll
            for (int mi = 0; mi < 4; ++mi) {
                int row = mi * 16 + lq;
                af[mi] = *reinterpret_cast<const bf16x8*>(AsB + row * 256 + c * 16);
            }
            {
                int row = w * 16 + lq;
                bfr = *reinterpret_cast<const bf16x8*>(BsB + row * 256 + c * 16);
            }
            __builtin_amdgcn_s_setprio(1);
#pragma unroll
            for (int mi = 0; mi < 4; ++mi)
                acc[mi] = __builtin_amdgcn_mfma_f32_16x16x32_bf16(
                    af[mi], bfr, acc[mi], 0, 0, 0);
            __builtin_amdgcn_s_setprio(0);
        }
    }

    const float bcol = jb.bias[n0 + w * 16 + lq];
    const int n = n0 + w * 16 + lq;

#pragma unroll
    for (int mi = 0; mi < 4; ++mi) {
        float v[4];
#pragma unroll
        for (int r = 0; r < 4; ++r) {
            float x = (acc[mi][r] + bcol) * jb.scale;
            if (jb.relu) x = fmaxf(x, 0.f);
            v[r] = x;
        }
        const int mbase = m0 + mi * 16 + 4 * g;
        if (jb.mode == 0) {
            float* C = (float*)jb.C;
#pragma unroll
            for (int r = 0; r < 4; ++r)
                C[(size_t)(mbase + r) * HID_ + n] = v[r];
        } else if (jb.mode == 1) {
            unsigned short* C = (unsigned short*)jb.C;
#pragma unroll
            for (int r = 0; r < 4; ++r)
                C[(size_t)(mbase + r) * HID_ + n] = f2bf(v[r]);
        } else {
            unsigned short* C = (unsigned short*)jb.C;
            const int bb = mbase >> 10, ltok = mbase & 1023;
            ushort4v o;
            o.x = f2bf(v[0]); o.y = f2bf(v[1]); o.z = f2bf(v[2]); o.w = f2bf(v[3]);
            *reinterpret_cast<ushort4v*>(&C[(size_t)(bb * HID_ + n) * L_ + ltok]) = o;
        }
    }
}

// ---------------------------------------------------------------------------
// Flash attention, bf16 MFMA, SWAPPED QK^T (unchanged from round 12/13).
// ---------------------------------------------------------------------------
__global__ __launch_bounds__(256, 3) void attn_mfma_kernel(
    const unsigned short* __restrict__ Qb, const unsigned short* __restrict__ Kb,
    const unsigned short* __restrict__ Vtb, const float* __restrict__ rel,
    const int* __restrict__ seq_len, const int* __restrict__ lex_num,
    unsigned short* __restrict__ ctx)
{
    const int qt = blockIdx.x, bh = blockIdx.y;
    const int b = bh / NH_, h = bh % NH_;
    const int q0 = qt * 64;
    const int sl = seq_len[b] + lex_num[0];
    const int nkt = (sl + 63) >> 6;

    __shared__ unsigned short Ks0[64 * 72], Ks1[64 * 72];
    __shared__ unsigned short Vs0[64 * 72], Vs1[64 * 72];
    __shared__ unsigned short Ps[64 * 72];

    const int tid = threadIdx.x;
    const int w = tid >> 6, lane = tid & 63, g = lane >> 4, lq = lane & 15;
    const int r0 = tid >> 3, cc0 = tid & 7;
    const int r1 = 32 + r0;

    const unsigned short* Kbase = Kb  + (size_t)(b * L_) * HID_ + h * D_;
    const unsigned short* Vbase = Vtb + (size_t)(b * HID_ + h * D_) * L_;
    const float* relbase = rel + (size_t)bh * (L_ * L_) + (size_t)(q0 + w * 16 + lq) * L_ + 4 * g;

    bf16x8 aq[2];
#pragma unroll
    for (int ks = 0; ks < 2; ++ks)
        aq[ks] = *reinterpret_cast<const bf16x8*>(
            &Qb[(size_t)(b * L_ + q0 + w * 16 + lq) * HID_ + h * D_ + ks * 32 + g * 8]);

    f32x4 acc[4];
#pragma unroll
    for (int i = 0; i < 4; ++i) acc[i] = (f32x4){0.f, 0.f, 0.f, 0.f};
    float m_r = -3e38f, l_r = 0.f;

    ushort8v kA0, kA1, vA0, vA1, kB0, kB1, vB0, vB1;
    f32x4 relA[4], relB[4];

    auto load_set = [&](int kt_, ushort8v& K0, ushort8v& K1, ushort8v& V0,
                        ushort8v& V1, f32x4 (&R)[4]) {
        const int k0 = kt_ * 64;
        K0 = *reinterpret_cast<const ushort8v*>(&Kbase[(size_t)(k0 + r0) * HID_ + cc0 * 8]);
        K1 = *reinterpret_cast<const ushort8v*>(&Kbase[(size_t)(k0 + r1) * HID_ + cc0 * 8]);
        V0 = *reinterpret_cast<const ushort8v*>(&Vbase[(size_t)r0 * L_ + k0 + cc0 * 8]);
        V1 = *reinterpret_cast<const ushort8v*>(&Vbase[(size_t)r1 * L_ + k0 + cc0 * 8]);
#pragma unroll
        for (int ni = 0; ni < 4; ++ni)
            R[ni] = *reinterpret_cast<const f32x4*>(&relbase[k0 + ni * 16]);
    };

    auto body = [&](int kt_, ushort8v& K0, ushort8v& K1, ushort8v& V0, ushort8v& V1,
                    f32x4 (&R)[4], unsigned short* KsC, unsigned short* VsC) {
        const int k0 = kt_ * 64;
        *reinterpret_cast<ushort8v*>(&KsC[r0 * 72 + cc0 * 8]) = K0;
        *reinterpret_cast<ushort8v*>(&KsC[r1 * 72 + cc0 * 8]) = K1;
        *reinterpret_cast<ushort8v*>(&VsC[r0 * 72 + cc0 * 8]) = V0;
        *reinterpret_cast<ushort8v*>(&VsC[r1 * 72 + cc0 * 8]) = V1;
        __syncthreads();

        {
            int tn = kt_ + 2; if (tn > nkt - 1) tn = nkt - 1;
            const int kn = tn * 64;
            K0 = *reinterpret_cast<const ushort8v*>(&Kbase[(size_t)(kn + r0) * HID_ + cc0 * 8]);
            K1 = *reinterpret_cast<const ushort8v*>(&Kbase[(size_t)(kn + r1) * HID_ + cc0 * 8]);
            V0 = *reinterpret_cast<const ushort8v*>(&Vbase[(size_t)r0 * L_ + kn + cc0 * 8]);
            V1 = *reinterpret_cast<const ushort8v*>(&Vbase[(size_t)r1 * L_ + kn + cc0 * 8]);
        }

        // S^T = K @ Q^T
        f32x4 s[4];
#pragma unroll
        for (int ni = 0; ni < 4; ++ni) s[ni] = (f32x4){0.f, 0.f, 0.f, 0.f};
        __builtin_amdgcn_s_setprio(1);
#pragma unroll
        for (int ks = 0; ks < 2; ++ks) {
#pragma unroll
            for (int ni = 0; ni < 4; ++ni) {
                bf16x8 bk = *reinterpret_cast<const bf16x8*>(
                    &KsC[(ni * 16 + lq) * 72 + ks * 32 + g * 8]);
                s[ni] = __builtin_amdgcn_mfma_f32_16x16x32_bf16(bk, aq[ks], s[ni], 0, 0, 0);
            }
        }
        __builtin_amdgcn_s_setprio(0);

        float sv[4][4];
#pragma unroll
        for (int ni = 0; ni < 4; ++ni) {
            const int colb = k0 + ni * 16 + 4 * g;
#pragma unroll
            for (int r = 0; r < 4; ++r)
                sv[ni][r] = (colb + r < sl) ? (s[ni][r] + R[ni][r]) : NEGV;
        }

        {
            int tn = kt_ + 2; if (tn > nkt - 1) tn = nkt - 1;
            const int kn = tn * 64;
#pragma unroll
            for (int ni = 0; ni < 4; ++ni)
                R[ni] = *reinterpret_cast<const f32x4*>(&relbase[kn + ni * 16]);
        }

        float rm = sv[0][0];
#pragma unroll
        for (int ni = 0; ni < 4; ++ni)
#pragma unroll
            for (int r = 0; r < 4; ++r) rm = fmaxf(rm, sv[ni][r]);
        rm = fmaxf(rm, __shfl_xor(rm, 16));
        rm = fmaxf(rm, __shfl_xor(rm, 32));
        const float mn = fmaxf(m_r, rm);
        const float sc = __expf(m_r - mn);
        float p[4][4];
        float rs = 0.f;
#pragma unroll
        for (int ni = 0; ni < 4; ++ni)
#pragma unroll
            for (int r = 0; r < 4; ++r) {
                p[ni][r] = __expf(sv[ni][r] - mn);
                rs += p[ni][r];
            }
        rs += __shfl_xor(rs, 16);
        rs += __shfl_xor(rs, 32);
        l_r = l_r * sc + rs;
        m_r = mn;
#pragma unroll
        for (int ni = 0; ni < 4; ++ni) acc[ni] *= sc;

#pragma unroll
        for (int ni = 0; ni < 4; ++ni) {
            ushort4v o;
            o.x = f2bf(p[ni][0]); o.y = f2bf(p[ni][1]);
            o.z = f2bf(p[ni][2]); o.w = f2bf(p[ni][3]);
            *reinterpret_cast<ushort4v*>(&Ps[(w * 16 + lq) * 72 + ni * 16 + 4 * g]) = o;
        }

        // O^T += V^T @ P^T
        __builtin_amdgcn_s_setprio(1);
#pragma unroll
        for (int ks = 0; ks < 2; ++ks) {
            bf16x8 ap = *reinterpret_cast<const bf16x8*>(
                &Ps[(w * 16 + lq) * 72 + ks * 32 + g * 8]);
#pragma unroll
            for (int ni = 0; ni < 4; ++ni) {
                bf16x8 bv = *reinterpret_cast<const bf16x8*>(
                    &VsC[(ni * 16 + lq) * 72 + ks * 32 + g * 8]);
                acc[ni] = __builtin_amdgcn_mfma_f32_16x16x32_bf16(bv, ap, acc[ni], 0, 0, 0);
            }
        }
        __builtin_amdgcn_s_setprio(0);
    };

    load_set(0, kA0, kA1, vA0, vA1, relA);
    load_set(nkt > 1 ? 1 : 0, kB0, kB1, vB0, vB1, relB);

    for (int kt = 0; kt < nkt; kt += 2) {
        body(kt, kA0, kA1, vA0, vA1, relA, Ks0, Vs0);
        if (kt + 1 < nkt)
            body(kt + 1, kB0, kB1, vB0, vB1, relB, Ks1, Vs1);
    }

    const float inv = 1.f / l_r;
    unsigned short* cbase = ctx + (size_t)(b * L_ + q0 + w * 16 + lq) * HID_ + h * D_;
#pragma unroll
    for (int ni = 0; ni < 4; ++ni) {
        ushort4v o;
        o.x = f2bf(acc[ni][0] * inv);
        o.y = f2bf(acc[ni][1] * inv);
        o.z = f2bf(acc[ni][2] * inv);
        o.w = f2bf(acc[ni][3] * inv);
        *reinterpret_cast<ushort4v*>(&cbase[ni * 16 + 4 * g]) = o;
    }
}

// ---------------------------------------------------------------------------
// LayerNorm(2*x) over rows of 768; out f32 or bf16.
// ---------------------------------------------------------------------------
__global__ __launch_bounds__(256) void ln2_kernel(
    const float* __restrict__ in, const float* __restrict__ g,
    const float* __restrict__ bta, void* __restrict__ out, int bf16out)
{
    const int row = blockIdx.x;
    const float* x = in + (size_t)row * HID_;
    const int tid = threadIdx.x;

    float vals[3];
    float s = 0.f, ss = 0.f;
#pragma unroll
    for (int j = 0; j < 3; ++j) {
        float t = 2.f * x[tid + j * 256];
        vals[j] = t;
        s += t;
        ss += t * t;
    }
#pragma unroll
    for (int m = 1; m < 64; m <<= 1) {
        s += __shfl_xor(s, m, 64);
        ss += __shfl_xor(ss, m, 64);
    }
    __shared__ float sb[4], ssb[4];
    if ((tid & 63) == 0) { sb[tid >> 6] = s; ssb[tid >> 6] = ss; }
    __syncthreads();
    s = sb[0] + sb[1] + sb[2] + sb[3];
    ss = ssb[0] + ssb[1] + ssb[2] + ssb[3];
    const float mean = s * (1.f / 768.f);
    float var = ss * (1.f / 768.f) - mean * mean;
    if (var < 0.f) var = 0.f;
    const float invs = rsqrtf(var + 1e-5f);
    if (bf16out) {
        unsigned short* o = (unsigned short*)out;
#pragma unroll
        for (int j = 0; j < 3; ++j) {
            int c = tid + j * 256;
            o[(size_t)row * HID_ + c] = f2bf((vals[j] - mean) * invs * g[c] + bta[c]);
        }
    } else {
        float* o = (float*)out;
#pragma unroll
        for (int j = 0; j < 3; ++j) {
            int c = tid + j * 256;
            o[(size_t)row * HID_ + c] = (vals[j] - mean) * invs * g[c] + bta[c];
        }
    }
}

// ---------------------------------------------------------------------------
extern "C" void kernel_launch(void* const* d_in, const int* in_sizes, int n_in,
                              void* d_out, int out_size, void* d_ws, size_t ws_size,
                              hipStream_t stream) {
    const float* inp     = (const float*)d_in[0];
    const int*   seq_len = (const int*)d_in[1];
    const int*   lex_num = (const int*)d_in[2];
    const float* rel     = (const float*)d_in[3];
    const float* Wq = (const float*)d_in[4];
    const float* bq = (const float*)d_in[5];
    const float* Wk = (const float*)d_in[6];
    const float* bk = (const float*)d_in[7];
    const float* Wv = (const float*)d_in[8];
    const float* bv = (const float*)d_in[9];
    const float* Wo = (const float*)d_in[10];
    const float* bo = (const float*)d_in[11];
    const float* W0 = (const float*)d_in[12];
    const float* b0 = (const float*)d_in[13];
    const float* W1 = (const float*)d_in[14];
    const float* b1 = (const float*)d_in[15];
    const float* ln_g = (const float*)d_in[16];
    const float* ln_b = (const float*)d_in[17];
    float* out = (float*)d_out;

    // ---- workspace carve (bytes) ----
    char* W = (char*)d_ws;
    const size_t WT_SZ = (size_t)HID_ * HID_ * 2;
    unsigned short* Wt[6];
    for (int i = 0; i < 6; ++i) Wt[i] = (unsigned short*)(W + i * WT_SZ);
    size_t off = 6 * WT_SZ;
    const size_t TOK_BF = (size_t)B_ * L_ * HID_ * 2;
    unsigned short* qb  = (unsigned short*)(W + off); off += TOK_BF;
    unsigned short* kb  = (unsigned short*)(W + off); off += TOK_BF;
    unsigned short* vtb = (unsigned short*)(W + off); off += TOK_BF;
    unsigned short* Eb  = (unsigned short*)(W + off); off += TOK_BF;
    float* Fbuf = (float*)(W + off);

    unsigned short* Xb   = Eb;
    unsigned short* ctxb = Eb;
    unsigned short* y2b  = vtb;
    unsigned short* hb   = qb;

    convert_x_kernel<<<dim3(3072), dim3(256), 0, stream>>>(inp, Xb, (B_ * L_ * HID_) / 4);

    {
        WArgs wa;
        const float* ws_[6] = {Wq, Wk, Wv, Wo, W0, W1};
        for (int i = 0; i < 6; ++i) { wa.w[i] = ws_[i]; wa.wt[i] = Wt[i]; }
        transpose_w_kernel<<<dim3(12, 12, 6), dim3(256), 0, stream>>>(wa);
    }

    {
        GemmArgs ga;
        ga.j[0] = {Xb, Wt[0], bq, (void*)qb,  1, 0, SCALE_};
        ga.j[1] = {Xb, Wt[1], bk, (void*)kb,  1, 0, 1.f};
        ga.j[2] = {Xb, Wt[2], bv, (void*)vtb, 2, 0, 1.f};
        gemm_bf16_kernel<<<dim3(64, 12, 3), dim3(256), 0, stream>>>(ga);
    }

    attn_mfma_kernel<<<dim3(16, 48), dim3(256), 0, stream>>>(
        qb, kb, vtb, rel, seq_len, lex_num, ctxb);

    {
        GemmArgs ga;
        ga.j[0] = {ctxb, Wt[3], bo, (void*)Fbuf, 0, 0, 1.f};
        gemm_bf16_kernel<<<dim3(64, 12, 1), dim3(256), 0, stream>>>(ga);
    }
    ln2_kernel<<<dim3(4096), dim3(256), 0, stream>>>(Fbuf, ln_g, ln_b, (void*)y2b, 1);
    {
        GemmArgs ga;
        ga.j[0] = {y2b, Wt[4], b0, (void*)hb, 1, 1, 1.f};
        gemm_bf16_kernel<<<dim3(64, 12, 1), dim3(256), 0, stream>>>(ga);
    }
    {
        GemmArgs ga;
        ga.j[0] = {hb, Wt[5], b1, (void*)Fbuf, 0, 0, 1.f};
        gemm_bf16_kernel<<<dim3(64, 12, 1), dim3(256), 0, stream>>>(ga);
    }
    ln2_kernel<<<dim3(4096), dim3(256), 0, stream>>>(Fbuf, ln_g, ln_b, (void*)out, 0);
}

// Round 16
// 123.148 us; speedup vs baseline: 1.3445x; 1.0149x over previous
//
#include <hip/hip_runtime.h>
#include <math.h>

#define B_   4
#define L_   1024
#define HID_ 768
#define NH_  12
#define D_   64
#define SCALE_ 0.125f
#define NEGV (-1e15f)

typedef __attribute__((ext_vector_type(4))) float  f32x4;
typedef __attribute__((ext_vector_type(8))) __bf16 bf16x8;
typedef __attribute__((ext_vector_type(8))) unsigned short ushort8v;
typedef __attribute__((ext_vector_type(4))) unsigned short ushort4v;

typedef const __attribute__((address_space(1))) unsigned int* gas1_t;
typedef __attribute__((address_space(3))) unsigned int*       las3_t;
#define GLDS16(g, l) __builtin_amdgcn_global_load_lds((gas1_t)(g), (las3_t)(l), 16, 0, 0)

static __device__ __forceinline__ unsigned short f2bf(float f) {
    unsigned int u = __builtin_bit_cast(unsigned int, f);
    u += 0x7fffu + ((u >> 16) & 1u);           // RNE
    return (unsigned short)(u >> 16);
}
static __device__ __forceinline__ float bf2f(unsigned short u) {
    unsigned int x = ((unsigned int)u) << 16;
    return __builtin_bit_cast(float, x);
}

// ---------------------------------------------------------------------------
// Fused prep kernel. grid (12,12,7):
//   z<6 : W f32 [768 in][768 out] -> Wt bf16 [768 out][768 in] (transpose)
//   z==6: inp f32 -> bf16 (grid-stride over 786432 float4 groups)
// ---------------------------------------------------------------------------
struct WArgs {
    const float* w[6]; unsigned short* wt[6];
    const float* xin; unsigned short* xout; int n4;
};

__global__ __launch_bounds__(256) void prep_kernel(WArgs a)
{
    const int tid = threadIdx.x;
    if (blockIdx.z == 6) {
        const int nblk = 144;
        int base = (blockIdx.y * 12 + blockIdx.x) * 256 + tid;
        for (int i = base; i < a.n4; i += nblk * 256) {
            float4 v = reinterpret_cast<const float4*>(a.xin)[i];
            ushort4v o;
            o.x = f2bf(v.x); o.y = f2bf(v.y); o.z = f2bf(v.z); o.w = f2bf(v.w);
            reinterpret_cast<ushort4v*>(a.xout)[i] = o;
        }
        return;
    }
    const float* W = a.w[blockIdx.z];
    unsigned short* Wt = a.wt[blockIdx.z];
    __shared__ float t[64][65];
    const int lr = tid >> 2, lc4 = (tid & 3) * 16;
    const int r0 = blockIdx.y * 64, c0 = blockIdx.x * 64;
#pragma unroll
    for (int j = 0; j < 4; ++j) {
        float4 v = *reinterpret_cast<const float4*>(&W[(size_t)(r0 + lr) * HID_ + c0 + lc4 + j * 4]);
        t[lr][lc4 + j * 4 + 0] = v.x;
        t[lr][lc4 + j * 4 + 1] = v.y;
        t[lr][lc4 + j * 4 + 2] = v.z;
        t[lr][lc4 + j * 4 + 3] = v.w;
    }
    __syncthreads();
    unsigned short tmp[16];
#pragma unroll
    for (int j = 0; j < 16; ++j) tmp[j] = f2bf(t[lc4 + j][lr]);
    unsigned short* dst = &Wt[(size_t)(c0 + lr) * HID_ + r0 + lc4];
    *reinterpret_cast<ushort8v*>(dst)     = *reinterpret_cast<ushort8v*>(&tmp[0]);
    *reinterpret_cast<ushort8v*>(dst + 8) = *reinterpret_cast<ushort8v*>(&tmp[8]);
}

// ---------------------------------------------------------------------------
// bf16 GEMM, 64x64 tile, BK=128 (6 iterations), 32 KB LDS (R15 structure).
// mode 0: f32 C ; mode 1: bf16 C ; mode 2: bf16 Vt[(b*768+n)*1024+l]
// ---------------------------------------------------------------------------
struct GemmJob {
    const unsigned short* A;
    const unsigned short* Wt;
    const float* bias;
    void* C;
    int mode;
    int relu;
    float scale;
};
struct GemmArgs { GemmJob j[3]; };

__global__ __launch_bounds__(256, 3) void gemm_bf16_kernel(GemmArgs args)
{
    const GemmJob jb = args.j[blockIdx.z];
    __shared__ unsigned short As[64 * 128];
    __shared__ unsigned short Bs[64 * 128];

    const int tid = threadIdx.x;
    const int w = tid >> 6, lane = tid & 63, g = lane >> 4, lq = lane & 15;
    const int m0 = blockIdx.x * 64, n0 = blockIdx.y * 64;

    f32x4 acc[4];
#pragma unroll
    for (int i = 0; i < 4; ++i) acc[i] = (f32x4){0.f, 0.f, 0.f, 0.f};

    const int rr = tid >> 4;
    const int kq = ((tid & 15) ^ rr) * 8;
    const unsigned short* Abase = jb.A  + (size_t)(m0 + rr) * HID_ + kq;
    const unsigned short* Bbase = jb.Wt + (size_t)(n0 + rr) * HID_ + kq;
    char* AsB = (char*)As;
    char* BsB = (char*)Bs;
    const int wb = w * 1024;

    for (int k0 = 0; k0 < HID_; k0 += 128) {
        __syncthreads();
#pragma unroll
        for (int j = 0; j < 4; ++j)
            GLDS16(Abase + (size_t)(j * 16) * HID_ + k0, AsB + j * 4096 + wb);
#pragma unroll
        for (int j = 0; j < 4; ++j)
            GLDS16(Bbase + (size_t)(j * 16) * HID_ + k0, BsB + j * 4096 + wb);
        __syncthreads();

#pragma unroll
        for (int ks = 0; ks < 4; ++ks) {
            bf16x8 af[4], bfr;
            const int c = (ks * 4 + g) ^ lq;
#pragma unroll
            for (int mi = 0; mi < 4; ++mi) {
                int row = mi * 16 + lq;
                af[mi] = *reinterpret_cast<const bf16x8*>(AsB + row * 256 + c * 16);
            }
            {
                int row = w * 16 + lq;
                bfr = *reinterpret_cast<const bf16x8*>(BsB + row * 256 + c * 16);
            }
            __builtin_amdgcn_s_setprio(1);
#pragma unroll
            for (int mi = 0; mi < 4; ++mi)
                acc[mi] = __builtin_amdgcn_mfma_f32_16x16x32_bf16(
                    af[mi], bfr, acc[mi], 0, 0, 0);
            __builtin_amdgcn_s_setprio(0);
        }
    }

    const float bcol = jb.bias[n0 + w * 16 + lq];
    const int n = n0 + w * 16 + lq;

#pragma unroll
    for (int mi = 0; mi < 4; ++mi) {
        float v[4];
#pragma unroll
        for (int r = 0; r < 4; ++r) {
            float x = (acc[mi][r] + bcol) * jb.scale;
            if (jb.relu) x = fmaxf(x, 0.f);
            v[r] = x;
        }
        const int mbase = m0 + mi * 16 + 4 * g;
        if (jb.mode == 0) {
            float* C = (float*)jb.C;
#pragma unroll
            for (int r = 0; r < 4; ++r)
                C[(size_t)(mbase + r) * HID_ + n] = v[r];
        } else if (jb.mode == 1) {
            unsigned short* C = (unsigned short*)jb.C;
#pragma unroll
            for (int r = 0; r < 4; ++r)
                C[(size_t)(mbase + r) * HID_ + n] = f2bf(v[r]);
        } else {
            unsigned short* C = (unsigned short*)jb.C;
            const int bb = mbase >> 10, ltok = mbase & 1023;
            ushort4v o;
            o.x = f2bf(v[0]); o.y = f2bf(v[1]); o.z = f2bf(v[2]); o.w = f2bf(v[3]);
            *reinterpret_cast<ushort4v*>(&C[(size_t)(bb * HID_ + n) * L_ + ltok]) = o;
        }
    }
}

// ---------------------------------------------------------------------------
// Flash attention, bf16 MFMA, SWAPPED QK^T (unchanged from rounds 12-15).
// ---------------------------------------------------------------------------
__global__ __launch_bounds__(256, 3) void attn_mfma_kernel(
    const unsigned short* __restrict__ Qb, const unsigned short* __restrict__ Kb,
    const unsigned short* __restrict__ Vtb, const float* __restrict__ rel,
    const int* __restrict__ seq_len, const int* __restrict__ lex_num,
    unsigned short* __restrict__ ctx)
{
    const int qt = blockIdx.x, bh = blockIdx.y;
    const int b = bh / NH_, h = bh % NH_;
    const int q0 = qt * 64;
    const int sl = seq_len[b] + lex_num[0];
    const int nkt = (sl + 63) >> 6;

    __shared__ unsigned short Ks0[64 * 72], Ks1[64 * 72];
    __shared__ unsigned short Vs0[64 * 72], Vs1[64 * 72];
    __shared__ unsigned short Ps[64 * 72];

    const int tid = threadIdx.x;
    const int w = tid >> 6, lane = tid & 63, g = lane >> 4, lq = lane & 15;
    const int r0 = tid >> 3, cc0 = tid & 7;
    const int r1 = 32 + r0;

    const unsigned short* Kbase = Kb  + (size_t)(b * L_) * HID_ + h * D_;
    const unsigned short* Vbase = Vtb + (size_t)(b * HID_ + h * D_) * L_;
    const float* relbase = rel + (size_t)bh * (L_ * L_) + (size_t)(q0 + w * 16 + lq) * L_ + 4 * g;

    bf16x8 aq[2];
#pragma unroll
    for (int ks = 0; ks < 2; ++ks)
        aq[ks] = *reinterpret_cast<const bf16x8*>(
            &Qb[(size_t)(b * L_ + q0 + w * 16 + lq) * HID_ + h * D_ + ks * 32 + g * 8]);

    f32x4 acc[4];
#pragma unroll
    for (int i = 0; i < 4; ++i) acc[i] = (f32x4){0.f, 0.f, 0.f, 0.f};
    float m_r = -3e38f, l_r = 0.f;

    ushort8v kA0, kA1, vA0, vA1, kB0, kB1, vB0, vB1;
    f32x4 relA[4], relB[4];

    auto load_set = [&](int kt_, ushort8v& K0, ushort8v& K1, ushort8v& V0,
                        ushort8v& V1, f32x4 (&R)[4]) {
        const int k0 = kt_ * 64;
        K0 = *reinterpret_cast<const ushort8v*>(&Kbase[(size_t)(k0 + r0) * HID_ + cc0 * 8]);
        K1 = *reinterpret_cast<const ushort8v*>(&Kbase[(size_t)(k0 + r1) * HID_ + cc0 * 8]);
        V0 = *reinterpret_cast<const ushort8v*>(&Vbase[(size_t)r0 * L_ + k0 + cc0 * 8]);
        V1 = *reinterpret_cast<const ushort8v*>(&Vbase[(size_t)r1 * L_ + k0 + cc0 * 8]);
#pragma unroll
        for (int ni = 0; ni < 4; ++ni)
            R[ni] = *reinterpret_cast<const f32x4*>(&relbase[k0 + ni * 16]);
    };

    auto body = [&](int kt_, ushort8v& K0, ushort8v& K1, ushort8v& V0, ushort8v& V1,
                    f32x4 (&R)[4], unsigned short* KsC, unsigned short* VsC) {
        const int k0 = kt_ * 64;
        *reinterpret_cast<ushort8v*>(&KsC[r0 * 72 + cc0 * 8]) = K0;
        *reinterpret_cast<ushort8v*>(&KsC[r1 * 72 + cc0 * 8]) = K1;
        *reinterpret_cast<ushort8v*>(&VsC[r0 * 72 + cc0 * 8]) = V0;
        *reinterpret_cast<ushort8v*>(&VsC[r1 * 72 + cc0 * 8]) = V1;
        __syncthreads();

        {
            int tn = kt_ + 2; if (tn > nkt - 1) tn = nkt - 1;
            const int kn = tn * 64;
            K0 = *reinterpret_cast<const ushort8v*>(&Kbase[(size_t)(kn + r0) * HID_ + cc0 * 8]);
            K1 = *reinterpret_cast<const ushort8v*>(&Kbase[(size_t)(kn + r1) * HID_ + cc0 * 8]);
            V0 = *reinterpret_cast<const ushort8v*>(&Vbase[(size_t)r0 * L_ + kn + cc0 * 8]);
            V1 = *reinterpret_cast<const ushort8v*>(&Vbase[(size_t)r1 * L_ + kn + cc0 * 8]);
        }

        // S^T = K @ Q^T
        f32x4 s[4];
#pragma unroll
        for (int ni = 0; ni < 4; ++ni) s[ni] = (f32x4){0.f, 0.f, 0.f, 0.f};
        __builtin_amdgcn_s_setprio(1);
#pragma unroll
        for (int ks = 0; ks < 2; ++ks) {
#pragma unroll
            for (int ni = 0; ni < 4; ++ni) {
                bf16x8 bk = *reinterpret_cast<const bf16x8*>(
                    &KsC[(ni * 16 + lq) * 72 + ks * 32 + g * 8]);
                s[ni] = __builtin_amdgcn_mfma_f32_16x16x32_bf16(bk, aq[ks], s[ni], 0, 0, 0);
            }
        }
        __builtin_amdgcn_s_setprio(0);

        float sv[4][4];
#pragma unroll
        for (int ni = 0; ni < 4; ++ni) {
            const int colb = k0 + ni * 16 + 4 * g;
#pragma unroll
            for (int r = 0; r < 4; ++r)
                sv[ni][r] = (colb + r < sl) ? (s[ni][r] + R[ni][r]) : NEGV;
        }

        {
            int tn = kt_ + 2; if (tn > nkt - 1) tn = nkt - 1;
            const int kn = tn * 64;
#pragma unroll
            for (int ni = 0; ni < 4; ++ni)
                R[ni] = *reinterpret_cast<const f32x4*>(&relbase[kn + ni * 16]);
        }

        float rm = sv[0][0];
#pragma unroll
        for (int ni = 0; ni < 4; ++ni)
#pragma unroll
            for (int r = 0; r < 4; ++r) rm = fmaxf(rm, sv[ni][r]);
        rm = fmaxf(rm, __shfl_xor(rm, 16));
        rm = fmaxf(rm, __shfl_xor(rm, 32));
        const float mn = fmaxf(m_r, rm);
        const float sc = __expf(m_r - mn);
        float p[4][4];
        float rs = 0.f;
#pragma unroll
        for (int ni = 0; ni < 4; ++ni)
#pragma unroll
            for (int r = 0; r < 4; ++r) {
                p[ni][r] = __expf(sv[ni][r] - mn);
                rs += p[ni][r];
            }
        rs += __shfl_xor(rs, 16);
        rs += __shfl_xor(rs, 32);
        l_r = l_r * sc + rs;
        m_r = mn;
#pragma unroll
        for (int ni = 0; ni < 4; ++ni) acc[ni] *= sc;

#pragma unroll
        for (int ni = 0; ni < 4; ++ni) {
            ushort4v o;
            o.x = f2bf(p[ni][0]); o.y = f2bf(p[ni][1]);
            o.z = f2bf(p[ni][2]); o.w = f2bf(p[ni][3]);
            *reinterpret_cast<ushort4v*>(&Ps[(w * 16 + lq) * 72 + ni * 16 + 4 * g]) = o;
        }

        // O^T += V^T @ P^T
        __builtin_amdgcn_s_setprio(1);
#pragma unroll
        for (int ks = 0; ks < 2; ++ks) {
            bf16x8 ap = *reinterpret_cast<const bf16x8*>(
                &Ps[(w * 16 + lq) * 72 + ks * 32 + g * 8]);
#pragma unroll
            for (int ni = 0; ni < 4; ++ni) {
                bf16x8 bv = *reinterpret_cast<const bf16x8*>(
                    &VsC[(ni * 16 + lq) * 72 + ks * 32 + g * 8]);
                acc[ni] = __builtin_amdgcn_mfma_f32_16x16x32_bf16(bv, ap, acc[ni], 0, 0, 0);
            }
        }
        __builtin_amdgcn_s_setprio(0);
    };

    load_set(0, kA0, kA1, vA0, vA1, relA);
    load_set(nkt > 1 ? 1 : 0, kB0, kB1, vB0, vB1, relB);

    for (int kt = 0; kt < nkt; kt += 2) {
        body(kt, kA0, kA1, vA0, vA1, relA, Ks0, Vs0);
        if (kt + 1 < nkt)
            body(kt + 1, kB0, kB1, vB0, vB1, relB, Ks1, Vs1);
    }

    const float inv = 1.f / l_r;
    unsigned short* cbase = ctx + (size_t)(b * L_ + q0 + w * 16 + lq) * HID_ + h * D_;
#pragma unroll
    for (int ni = 0; ni < 4; ++ni) {
        ushort4v o;
        o.x = f2bf(acc[ni][0] * inv);
        o.y = f2bf(acc[ni][1] * inv);
        o.z = f2bf(acc[ni][2] * inv);
        o.w = f2bf(acc[ni][3] * inv);
        *reinterpret_cast<ushort4v*>(&cbase[ni * 16 + 4 * g]) = o;
    }
}

// ---------------------------------------------------------------------------
// LayerNorm(2*x) over rows of 768, bf16 input; out f32 or bf16.
// ---------------------------------------------------------------------------
__global__ __launch_bounds__(256) void ln2_kernel(
    const unsigned short* __restrict__ in, const float* __restrict__ g,
    const float* __restrict__ bta, void* __restrict__ out, int bf16out)
{
    const int row = blockIdx.x;
    const unsigned short* x = in + (size_t)row * HID_;
    const int tid = threadIdx.x;

    float vals[3];
    float s = 0.f, ss = 0.f;
#pragma unroll
    for (int j = 0; j < 3; ++j) {
        float t = 2.f * bf2f(x[tid + j * 256]);
        vals[j] = t;
        s += t;
        ss += t * t;
    }
#pragma unroll
    for (int m = 1; m < 64; m <<= 1) {
        s += __shfl_xor(s, m, 64);
        ss += __shfl_xor(ss, m, 64);
    }
    __shared__ float sb[4], ssb[4];
    if ((tid & 63) == 0) { sb[tid >> 6] = s; ssb[tid >> 6] = ss; }
    __syncthreads();
    s = sb[0] + sb[1] + sb[2] + sb[3];
    ss = ssb[0] + ssb[1] + ssb[2] + ssb[3];
    const float mean = s * (1.f / 768.f);
    float var = ss * (1.f / 768.f) - mean * mean;
    if (var < 0.f) var = 0.f;
    const float invs = rsqrtf(var + 1e-5f);
    if (bf16out) {
        unsigned short* o = (unsigned short*)out;
#pragma unroll
        for (int j = 0; j < 3; ++j) {
            int c = tid + j * 256;
            o[(size_t)row * HID_ + c] = f2bf((vals[j] - mean) * invs * g[c] + bta[c]);
        }
    } else {
        float* o = (float*)out;
#pragma unroll
        for (int j = 0; j < 3; ++j) {
            int c = tid + j * 256;
            o[(size_t)row * HID_ + c] = (vals[j] - mean) * invs * g[c] + bta[c];
        }
    }
}

// ---------------------------------------------------------------------------
extern "C" void kernel_launch(void* const* d_in, const int* in_sizes, int n_in,
                              void* d_out, int out_size, void* d_ws, size_t ws_size,
                              hipStream_t stream) {
    const float* inp     = (const float*)d_in[0];
    const int*   seq_len = (const int*)d_in[1];
    const int*   lex_num = (const int*)d_in[2];
    const float* rel     = (const float*)d_in[3];
    const float* Wq = (const float*)d_in[4];
    const float* bq = (const float*)d_in[5];
    const float* Wk = (const float*)d_in[6];
    const float* bk = (const float*)d_in[7];
    const float* Wv = (const float*)d_in[8];
    const float* bv = (const float*)d_in[9];
    const float* Wo = (const float*)d_in[10];
    const float* bo = (const float*)d_in[11];
    const float* W0 = (const float*)d_in[12];
    const float* b0 = (const float*)d_in[13];
    const float* W1 = (const float*)d_in[14];
    const float* b1 = (const float*)d_in[15];
    const float* ln_g = (const float*)d_in[16];
    const float* ln_b = (const float*)d_in[17];
    float* out = (float*)d_out;

    // ---- workspace carve (bytes) ----
    char* W = (char*)d_ws;
    const size_t WT_SZ = (size_t)HID_ * HID_ * 2;
    unsigned short* Wt[6];
    for (int i = 0; i < 6; ++i) Wt[i] = (unsigned short*)(W + i * WT_SZ);
    size_t off = 6 * WT_SZ;
    const size_t TOK_BF = (size_t)B_ * L_ * HID_ * 2;
    unsigned short* qb  = (unsigned short*)(W + off); off += TOK_BF;
    unsigned short* kb  = (unsigned short*)(W + off); off += TOK_BF;
    unsigned short* vtb = (unsigned short*)(W + off); off += TOK_BF;
    unsigned short* Eb  = (unsigned short*)(W + off); off += TOK_BF;

    // buffer reuse schedule (all bf16 now):
    unsigned short* Xb   = Eb;    // inp bf16 (consumed by QKV)
    unsigned short* ctxb = Eb;    // attn out (overwrites Xb after use)
    unsigned short* ybf  = kb;    // y = ctx@Wo+bo     (kb free after attn)
    unsigned short* y2b  = vtb;   // LN(2y)            (vtb free after attn)
    unsigned short* hb   = qb;    // relu(y2@W0+b0)    (qb free after attn)
    unsigned short* h2bf = kb;    // h@W1+b1           (kb free after LN#1)

    {
        WArgs wa;
        const float* ws_[6] = {Wq, Wk, Wv, Wo, W0, W1};
        for (int i = 0; i < 6; ++i) { wa.w[i] = ws_[i]; wa.wt[i] = Wt[i]; }
        wa.xin = inp; wa.xout = Xb; wa.n4 = (B_ * L_ * HID_) / 4;
        prep_kernel<<<dim3(12, 12, 7), dim3(256), 0, stream>>>(wa);
    }

    {
        GemmArgs ga;
        ga.j[0] = {Xb, Wt[0], bq, (void*)qb,  1, 0, SCALE_};
        ga.j[1] = {Xb, Wt[1], bk, (void*)kb,  1, 0, 1.f};
        ga.j[2] = {Xb, Wt[2], bv, (void*)vtb, 2, 0, 1.f};
        gemm_bf16_kernel<<<dim3(64, 12, 3), dim3(256), 0, stream>>>(ga);
    }

    attn_mfma_kernel<<<dim3(16, 48), dim3(256), 0, stream>>>(
        qb, kb, vtb, rel, seq_len, lex_num, ctxb);

    {
        GemmArgs ga;
        ga.j[0] = {ctxb, Wt[3], bo, (void*)ybf, 1, 0, 1.f};
        gemm_bf16_kernel<<<dim3(64, 12, 1), dim3(256), 0, stream>>>(ga);
    }
    ln2_kernel<<<dim3(4096), dim3(256), 0, stream>>>(ybf, ln_g, ln_b, (void*)y2b, 1);
    {
        GemmArgs ga;
        ga.j[0] = {y2b, Wt[4], b0, (void*)hb, 1, 1, 1.f};
        gemm_bf16_kernel<<<dim3(64, 12, 1), dim3(256), 0, stream>>>(ga);
    }
    {
        GemmArgs ga;
        ga.j[0] = {hb, Wt[5], b1, (void*)h2bf, 1, 0, 1.f};
        gemm_bf16_kernel<<<dim3(64, 12, 1), dim3(256), 0, stream>>>(ga);
    }
    ln2_kernel<<<dim3(4096), dim3(256), 0, stream>>>(h2bf, ln_g, ln_b, (void*)out, 0);
}

// Round 17
// 115.489 us; speedup vs baseline: 1.4336x; 1.0663x over previous
//
#include <hip/hip_runtime.h>
#include <math.h>

#define B_   4
#define L_   1024
#define HID_ 768
#define NH_  12
#define D_   64
#define SCALE_ 0.125f
#define NEGV (-1e15f)

typedef __attribute__((ext_vector_type(4))) float  f32x4;
typedef __attribute__((ext_vector_type(8))) __bf16 bf16x8;
typedef __attribute__((ext_vector_type(8))) unsigned short ushort8v;
typedef __attribute__((ext_vector_type(4))) unsigned short ushort4v;

typedef const __attribute__((address_space(1))) unsigned int* gas1_t;
typedef __attribute__((address_space(3))) unsigned int*       las3_t;
#define GLDS16(g, l) __builtin_amdgcn_global_load_lds((gas1_t)(g), (las3_t)(l), 16, 0, 0)

static __device__ __forceinline__ unsigned short f2bf(float f) {
    unsigned int u = __builtin_bit_cast(unsigned int, f);
    u += 0x7fffu + ((u >> 16) & 1u);           // RNE
    return (unsigned short)(u >> 16);
}
static __device__ __forceinline__ float bf2f(unsigned short u) {
    unsigned int x = ((unsigned int)u) << 16;
    return __builtin_bit_cast(float, x);
}

// ---------------------------------------------------------------------------
// Fused prep kernel. grid (12,12,7):
//   z<6 : W f32 [768 in][768 out] -> Wt bf16 [768 out][768 in] (transpose)
//   z==6: inp f32 -> bf16 (grid-stride over 786432 float4 groups)
// ---------------------------------------------------------------------------
struct WArgs {
    const float* w[6]; unsigned short* wt[6];
    const float* xin; unsigned short* xout; int n4;
};

__global__ __launch_bounds__(256) void prep_kernel(WArgs a)
{
    const int tid = threadIdx.x;
    if (blockIdx.z == 6) {
        const int nblk = 144;
        int base = (blockIdx.y * 12 + blockIdx.x) * 256 + tid;
        for (int i = base; i < a.n4; i += nblk * 256) {
            float4 v = reinterpret_cast<const float4*>(a.xin)[i];
            ushort4v o;
            o.x = f2bf(v.x); o.y = f2bf(v.y); o.z = f2bf(v.z); o.w = f2bf(v.w);
            reinterpret_cast<ushort4v*>(a.xout)[i] = o;
        }
        return;
    }
    const float* W = a.w[blockIdx.z];
    unsigned short* Wt = a.wt[blockIdx.z];
    __shared__ float t[64][65];
    const int lr = tid >> 2, lc4 = (tid & 3) * 16;
    const int r0 = blockIdx.y * 64, c0 = blockIdx.x * 64;
#pragma unroll
    for (int j = 0; j < 4; ++j) {
        float4 v = *reinterpret_cast<const float4*>(&W[(size_t)(r0 + lr) * HID_ + c0 + lc4 + j * 4]);
        t[lr][lc4 + j * 4 + 0] = v.x;
        t[lr][lc4 + j * 4 + 1] = v.y;
        t[lr][lc4 + j * 4 + 2] = v.z;
        t[lr][lc4 + j * 4 + 3] = v.w;
    }
    __syncthreads();
    unsigned short tmp[16];
#pragma unroll
    for (int j = 0; j < 16; ++j) tmp[j] = f2bf(t[lc4 + j][lr]);
    unsigned short* dst = &Wt[(size_t)(c0 + lr) * HID_ + r0 + lc4];
    *reinterpret_cast<ushort8v*>(dst)     = *reinterpret_cast<ushort8v*>(&tmp[0]);
    *reinterpret_cast<ushort8v*>(dst + 8) = *reinterpret_cast<ushort8v*>(&tmp[8]);
}

// ---------------------------------------------------------------------------
// bf16 GEMM, 64x64 tile, BK=128 (6 iterations), 32 KB LDS (R15 structure).
// mode 0: f32 C ; mode 1: bf16 C ; mode 2: bf16 Vt[(b*768+n)*1024+l]
// ---------------------------------------------------------------------------
struct GemmJob {
    const unsigned short* A;
    const unsigned short* Wt;
    const float* bias;
    void* C;
    int mode;
    int relu;
    float scale;
};
struct GemmArgs { GemmJob j[3]; };

__global__ __launch_bounds__(256, 3) void gemm_bf16_kernel(GemmArgs args)
{
    const GemmJob jb = args.j[blockIdx.z];
    __shared__ unsigned short As[64 * 128];
    __shared__ unsigned short Bs[64 * 128];

    const int tid = threadIdx.x;
    const int w = tid >> 6, lane = tid & 63, g = lane >> 4, lq = lane & 15;
    const int m0 = blockIdx.x * 64, n0 = blockIdx.y * 64;

    f32x4 acc[4];
#pragma unroll
    for (int i = 0; i < 4; ++i) acc[i] = (f32x4){0.f, 0.f, 0.f, 0.f};

    const int rr = tid >> 4;
    const int kq = ((tid & 15) ^ rr) * 8;
    const unsigned short* Abase = jb.A  + (size_t)(m0 + rr) * HID_ + kq;
    const unsigned short* Bbase = jb.Wt + (size_t)(n0 + rr) * HID_ + kq;
    char* AsB = (char*)As;
    char* BsB = (char*)Bs;
    const int wb = w * 1024;

    for (int k0 = 0; k0 < HID_; k0 += 128) {
        __syncthreads();
#pragma unroll
        for (int j = 0; j < 4; ++j)
            GLDS16(Abase + (size_t)(j * 16) * HID_ + k0, AsB + j * 4096 + wb);
#pragma unroll
        for (int j = 0; j < 4; ++j)
            GLDS16(Bbase + (size_t)(j * 16) * HID_ + k0, BsB + j * 4096 + wb);
        __syncthreads();

#pragma unroll
        for (int ks = 0; ks < 4; ++ks) {
            bf16x8 af[4], bfr;
            const int c = (ks * 4 + g) ^ lq;
#pragma unroll
            for (int mi = 0; mi < 4; ++mi) {
                int row = mi * 16 + lq;
                af[mi] = *reinterpret_cast<const bf16x8*>(AsB + row * 256 + c * 16);
            }
            {
                int row = w * 16 + lq;
                bfr = *reinterpret_cast<const bf16x8*>(BsB + row * 256 + c * 16);
            }
            __builtin_amdgcn_s_setprio(1);
#pragma unroll
            for (int mi = 0; mi < 4; ++mi)
                acc[mi] = __builtin_amdgcn_mfma_f32_16x16x32_bf16(
                    af[mi], bfr, acc[mi], 0, 0, 0);
            __builtin_amdgcn_s_setprio(0);
        }
    }

    const float bcol = jb.bias[n0 + w * 16 + lq];
    const int n = n0 + w * 16 + lq;

#pragma unroll
    for (int mi = 0; mi < 4; ++mi) {
        float v[4];
#pragma unroll
        for (int r = 0; r < 4; ++r) {
            float x = (acc[mi][r] + bcol) * jb.scale;
            if (jb.relu) x = fmaxf(x, 0.f);
            v[r] = x;
        }
        const int mbase = m0 + mi * 16 + 4 * g;
        if (jb.mode == 0) {
            float* C = (float*)jb.C;
#pragma unroll
            for (int r = 0; r < 4; ++r)
                C[(size_t)(mbase + r) * HID_ + n] = v[r];
        } else if (jb.mode == 1) {
            unsigned short* C = (unsigned short*)jb.C;
#pragma unroll
            for (int r = 0; r < 4; ++r)
                C[(size_t)(mbase + r) * HID_ + n] = f2bf(v[r]);
        } else {
            unsigned short* C = (unsigned short*)jb.C;
            const int bb = mbase >> 10, ltok = mbase & 1023;
            ushort4v o;
            o.x = f2bf(v[0]); o.y = f2bf(v[1]); o.z = f2bf(v[2]); o.w = f2bf(v[3]);
            *reinterpret_cast<ushort4v*>(&C[(size_t)(bb * HID_ + n) * L_ + ltok]) = o;
        }
    }
}

// ---------------------------------------------------------------------------
// Flash attention, bf16 MFMA, SWAPPED QK^T + XCD-grouped grid:
//  - flat grid 768; xcd = d%8, k = d/8, bh = xcd + 8*(k/16), qt = k%16.
//    All 16 q-tiles of one (b,h) land on ONE XCD -> its 256 KB K/V stays
//    L2-resident (6 heads x 256 KB = 1.5 MB per 4 MB XCD L2). Bijective
//    (768 % 8 == 0). Pure locality heuristic - correctness unaffected.
//  - kernel body unchanged from rounds 12-16.
// ---------------------------------------------------------------------------
__global__ __launch_bounds__(256, 3) void attn_mfma_kernel(
    const unsigned short* __restrict__ Qb, const unsigned short* __restrict__ Kb,
    const unsigned short* __restrict__ Vtb, const float* __restrict__ rel,
    const int* __restrict__ seq_len, const int* __restrict__ lex_num,
    unsigned short* __restrict__ ctx)
{
    const int d = blockIdx.x;
    const int xcd = d & 7, kk = d >> 3;
    const int bh = xcd + 8 * (kk >> 4);
    const int qt = kk & 15;
    const int b = bh / NH_, h = bh % NH_;
    const int q0 = qt * 64;
    const int sl = seq_len[b] + lex_num[0];
    const int nkt = (sl + 63) >> 6;

    __shared__ unsigned short Ks0[64 * 72], Ks1[64 * 72];
    __shared__ unsigned short Vs0[64 * 72], Vs1[64 * 72];
    __shared__ unsigned short Ps[64 * 72];

    const int tid = threadIdx.x;
    const int w = tid >> 6, lane = tid & 63, g = lane >> 4, lq = lane & 15;
    const int r0 = tid >> 3, cc0 = tid & 7;
    const int r1 = 32 + r0;

    const unsigned short* Kbase = Kb  + (size_t)(b * L_) * HID_ + h * D_;
    const unsigned short* Vbase = Vtb + (size_t)(b * HID_ + h * D_) * L_;
    const float* relbase = rel + (size_t)bh * (L_ * L_) + (size_t)(q0 + w * 16 + lq) * L_ + 4 * g;

    bf16x8 aq[2];
#pragma unroll
    for (int ks = 0; ks < 2; ++ks)
        aq[ks] = *reinterpret_cast<const bf16x8*>(
            &Qb[(size_t)(b * L_ + q0 + w * 16 + lq) * HID_ + h * D_ + ks * 32 + g * 8]);

    f32x4 acc[4];
#pragma unroll
    for (int i = 0; i < 4; ++i) acc[i] = (f32x4){0.f, 0.f, 0.f, 0.f};
    float m_r = -3e38f, l_r = 0.f;

    ushort8v kA0, kA1, vA0, vA1, kB0, kB1, vB0, vB1;
    f32x4 relA[4], relB[4];

    auto load_set = [&](int kt_, ushort8v& K0, ushort8v& K1, ushort8v& V0,
                        ushort8v& V1, f32x4 (&R)[4]) {
        const int k0 = kt_ * 64;
        K0 = *reinterpret_cast<const ushort8v*>(&Kbase[(size_t)(k0 + r0) * HID_ + cc0 * 8]);
        K1 = *reinterpret_cast<const ushort8v*>(&Kbase[(size_t)(k0 + r1) * HID_ + cc0 * 8]);
        V0 = *reinterpret_cast<const ushort8v*>(&Vbase[(size_t)r0 * L_ + k0 + cc0 * 8]);
        V1 = *reinterpret_cast<const ushort8v*>(&Vbase[(size_t)r1 * L_ + k0 + cc0 * 8]);
#pragma unroll
        for (int ni = 0; ni < 4; ++ni)
            R[ni] = *reinterpret_cast<const f32x4*>(&relbase[k0 + ni * 16]);
    };

    auto body = [&](int kt_, ushort8v& K0, ushort8v& K1, ushort8v& V0, ushort8v& V1,
                    f32x4 (&R)[4], unsigned short* KsC, unsigned short* VsC) {
        const int k0 = kt_ * 64;
        *reinterpret_cast<ushort8v*>(&KsC[r0 * 72 + cc0 * 8]) = K0;
        *reinterpret_cast<ushort8v*>(&KsC[r1 * 72 + cc0 * 8]) = K1;
        *reinterpret_cast<ushort8v*>(&VsC[r0 * 72 + cc0 * 8]) = V0;
        *reinterpret_cast<ushort8v*>(&VsC[r1 * 72 + cc0 * 8]) = V1;
        __syncthreads();

        {
            int tn = kt_ + 2; if (tn > nkt - 1) tn = nkt - 1;
            const int kn = tn * 64;
            K0 = *reinterpret_cast<const ushort8v*>(&Kbase[(size_t)(kn + r0) * HID_ + cc0 * 8]);
            K1 = *reinterpret_cast<const ushort8v*>(&Kbase[(size_t)(kn + r1) * HID_ + cc0 * 8]);
            V0 = *reinterpret_cast<const ushort8v*>(&Vbase[(size_t)r0 * L_ + kn + cc0 * 8]);
            V1 = *reinterpret_cast<const ushort8v*>(&Vbase[(size_t)r1 * L_ + kn + cc0 * 8]);
        }

        // S^T = K @ Q^T
        f32x4 s[4];
#pragma unroll
        for (int ni = 0; ni < 4; ++ni) s[ni] = (f32x4){0.f, 0.f, 0.f, 0.f};
        __builtin_amdgcn_s_setprio(1);
#pragma unroll
        for (int ks = 0; ks < 2; ++ks) {
#pragma unroll
            for (int ni = 0; ni < 4; ++ni) {
                bf16x8 bk = *reinterpret_cast<const bf16x8*>(
                    &KsC[(ni * 16 + lq) * 72 + ks * 32 + g * 8]);
                s[ni] = __builtin_amdgcn_mfma_f32_16x16x32_bf16(bk, aq[ks], s[ni], 0, 0, 0);
            }
        }
        __builtin_amdgcn_s_setprio(0);

        float sv[4][4];
#pragma unroll
        for (int ni = 0; ni < 4; ++ni) {
            const int colb = k0 + ni * 16 + 4 * g;
#pragma unroll
            for (int r = 0; r < 4; ++r)
                sv[ni][r] = (colb + r < sl) ? (s[ni][r] + R[ni][r]) : NEGV;
        }

        {
            int tn = kt_ + 2; if (tn > nkt - 1) tn = nkt - 1;
            const int kn = tn * 64;
#pragma unroll
            for (int ni = 0; ni < 4; ++ni)
                R[ni] = *reinterpret_cast<const f32x4*>(&relbase[kn + ni * 16]);
        }

        float rm = sv[0][0];
#pragma unroll
        for (int ni = 0; ni < 4; ++ni)
#pragma unroll
            for (int r = 0; r < 4; ++r) rm = fmaxf(rm, sv[ni][r]);
        rm = fmaxf(rm, __shfl_xor(rm, 16));
        rm = fmaxf(rm, __shfl_xor(rm, 32));
        const float mn = fmaxf(m_r, rm);
        const float sc = __expf(m_r - mn);
        float p[4][4];
        float rs = 0.f;
#pragma unroll
        for (int ni = 0; ni < 4; ++ni)
#pragma unroll
            for (int r = 0; r < 4; ++r) {
                p[ni][r] = __expf(sv[ni][r] - mn);
                rs += p[ni][r];
            }
        rs += __shfl_xor(rs, 16);
        rs += __shfl_xor(rs, 32);
        l_r = l_r * sc + rs;
        m_r = mn;
#pragma unroll
        for (int ni = 0; ni < 4; ++ni) acc[ni] *= sc;

#pragma unroll
        for (int ni = 0; ni < 4; ++ni) {
            ushort4v o;
            o.x = f2bf(p[ni][0]); o.y = f2bf(p[ni][1]);
            o.z = f2bf(p[ni][2]); o.w = f2bf(p[ni][3]);
            *reinterpret_cast<ushort4v*>(&Ps[(w * 16 + lq) * 72 + ni * 16 + 4 * g]) = o;
        }

        // O^T += V^T @ P^T
        __builtin_amdgcn_s_setprio(1);
#pragma unroll
        for (int ks = 0; ks < 2; ++ks) {
            bf16x8 ap = *reinterpret_cast<const bf16x8*>(
                &Ps[(w * 16 + lq) * 72 + ks * 32 + g * 8]);
#pragma unroll
            for (int ni = 0; ni < 4; ++ni) {
                bf16x8 bv = *reinterpret_cast<const bf16x8*>(
                    &VsC[(ni * 16 + lq) * 72 + ks * 32 + g * 8]);
                acc[ni] = __builtin_amdgcn_mfma_f32_16x16x32_bf16(bv, ap, acc[ni], 0, 0, 0);
            }
        }
        __builtin_amdgcn_s_setprio(0);
    };

    load_set(0, kA0, kA1, vA0, vA1, relA);
    load_set(nkt > 1 ? 1 : 0, kB0, kB1, vB0, vB1, relB);

    for (int kt = 0; kt < nkt; kt += 2) {
        body(kt, kA0, kA1, vA0, vA1, relA, Ks0, Vs0);
        if (kt + 1 < nkt)
            body(kt + 1, kB0, kB1, vB0, vB1, relB, Ks1, Vs1);
    }

    const float inv = 1.f / l_r;
    unsigned short* cbase = ctx + (size_t)(b * L_ + q0 + w * 16 + lq) * HID_ + h * D_;
#pragma unroll
    for (int ni = 0; ni < 4; ++ni) {
        ushort4v o;
        o.x = f2bf(acc[ni][0] * inv);
        o.y = f2bf(acc[ni][1] * inv);
        o.z = f2bf(acc[ni][2] * inv);
        o.w = f2bf(acc[ni][3] * inv);
        *reinterpret_cast<ushort4v*>(&cbase[ni * 16 + 4 * g]) = o;
    }
}

// ---------------------------------------------------------------------------
// LayerNorm(2*x) over rows of 768, bf16 input; out f32 or bf16.
// ---------------------------------------------------------------------------
__global__ __launch_bounds__(256) void ln2_kernel(
    const unsigned short* __restrict__ in, const float* __restrict__ g,
    const float* __restrict__ bta, void* __restrict__ out, int bf16out)
{
    const int row = blockIdx.x;
    const unsigned short* x = in + (size_t)row * HID_;
    const int tid = threadIdx.x;

    float vals[3];
    float s = 0.f, ss = 0.f;
#pragma unroll
    for (int j = 0; j < 3; ++j) {
        float t = 2.f * bf2f(x[tid + j * 256]);
        vals[j] = t;
        s += t;
        ss += t * t;
    }
#pragma unroll
    for (int m = 1; m < 64; m <<= 1) {
        s += __shfl_xor(s, m, 64);
        ss += __shfl_xor(ss, m, 64);
    }
    __shared__ float sb[4], ssb[4];
    if ((tid & 63) == 0) { sb[tid >> 6] = s; ssb[tid >> 6] = ss; }
    __syncthreads();
    s = sb[0] + sb[1] + sb[2] + sb[3];
    ss = ssb[0] + ssb[1] + ssb[2] + ssb[3];
    const float mean = s * (1.f / 768.f);
    float var = ss * (1.f / 768.f) - mean * mean;
    if (var < 0.f) var = 0.f;
    const float invs = rsqrtf(var + 1e-5f);
    if (bf16out) {
        unsigned short* o = (unsigned short*)out;
#pragma unroll
        for (int j = 0; j < 3; ++j) {
            int c = tid + j * 256;
            o[(size_t)row * HID_ + c] = f2bf((vals[j] - mean) * invs * g[c] + bta[c]);
        }
    } else {
        float* o = (float*)out;
#pragma unroll
        for (int j = 0; j < 3; ++j) {
            int c = tid + j * 256;
            o[(size_t)row * HID_ + c] = (vals[j] - mean) * invs * g[c] + bta[c];
        }
    }
}

// ---------------------------------------------------------------------------
extern "C" void kernel_launch(void* const* d_in, const int* in_sizes, int n_in,
                              void* d_out, int out_size, void* d_ws, size_t ws_size,
                              hipStream_t stream) {
    const float* inp     = (const float*)d_in[0];
    const int*   seq_len = (const int*)d_in[1];
    const int*   lex_num = (const int*)d_in[2];
    const float* rel     = (const float*)d_in[3];
    const float* Wq = (const float*)d_in[4];
    const float* bq = (const float*)d_in[5];
    const float* Wk = (const float*)d_in[6];
    const float* bk = (const float*)d_in[7];
    const float* Wv = (const float*)d_in[8];
    const float* bv = (const float*)d_in[9];
    const float* Wo = (const float*)d_in[10];
    const float* bo = (const float*)d_in[11];
    const float* W0 = (const float*)d_in[12];
    const float* b0 = (const float*)d_in[13];
    const float* W1 = (const float*)d_in[14];
    const float* b1 = (const float*)d_in[15];
    const float* ln_g = (const float*)d_in[16];
    const float* ln_b = (const float*)d_in[17];
    float* out = (float*)d_out;

    // ---- workspace carve (bytes) ----
    char* W = (char*)d_ws;
    const size_t WT_SZ = (size_t)HID_ * HID_ * 2;
    unsigned short* Wt[6];
    for (int i = 0; i < 6; ++i) Wt[i] = (unsigned short*)(W + i * WT_SZ);
    size_t off = 6 * WT_SZ;
    const size_t TOK_BF = (size_t)B_ * L_ * HID_ * 2;
    unsigned short* qb  = (unsigned short*)(W + off); off += TOK_BF;
    unsigned short* kb  = (unsigned short*)(W + off); off += TOK_BF;
    unsigned short* vtb = (unsigned short*)(W + off); off += TOK_BF;
    unsigned short* Eb  = (unsigned short*)(W + off); off += TOK_BF;

    unsigned short* Xb   = Eb;
    unsigned short* ctxb = Eb;
    unsigned short* ybf  = kb;
    unsigned short* y2b  = vtb;
    unsigned short* hb   = qb;
    unsigned short* h2bf = kb;

    {
        WArgs wa;
        const float* ws_[6] = {Wq, Wk, Wv, Wo, W0, W1};
        for (int i = 0; i < 6; ++i) { wa.w[i] = ws_[i]; wa.wt[i] = Wt[i]; }
        wa.xin = inp; wa.xout = Xb; wa.n4 = (B_ * L_ * HID_) / 4;
        prep_kernel<<<dim3(12, 12, 7), dim3(256), 0, stream>>>(wa);
    }

    {
        GemmArgs ga;
        ga.j[0] = {Xb, Wt[0], bq, (void*)qb,  1, 0, SCALE_};
        ga.j[1] = {Xb, Wt[1], bk, (void*)kb,  1, 0, 1.f};
        ga.j[2] = {Xb, Wt[2], bv, (void*)vtb, 2, 0, 1.f};
        gemm_bf16_kernel<<<dim3(64, 12, 3), dim3(256), 0, stream>>>(ga);
    }

    attn_mfma_kernel<<<dim3(768), dim3(256), 0, stream>>>(
        qb, kb, vtb, rel, seq_len, lex_num, ctxb);

    {
        GemmArgs ga;
        ga.j[0] = {ctxb, Wt[3], bo, (void*)ybf, 1, 0, 1.f};
        gemm_bf16_kernel<<<dim3(64, 12, 1), dim3(256), 0, stream>>>(ga);
    }
    ln2_kernel<<<dim3(4096), dim3(256), 0, stream>>>(ybf, ln_g, ln_b, (void*)y2b, 1);
    {
        GemmArgs ga;
        ga.j[0] = {y2b, Wt[4], b0, (void*)hb, 1, 1, 1.f};
        gemm_bf16_kernel<<<dim3(64, 12, 1), dim3(256), 0, stream>>>(ga);
    }
    {
        GemmArgs ga;
        ga.j[0] = {hb, Wt[5], b1, (void*)h2bf, 1, 0, 1.f};
        gemm_bf16_kernel<<<dim3(64, 12, 1), dim3(256), 0, stream>>>(ga);
    }
    ln2_kernel<<<dim3(4096), dim3(256), 0, stream>>>(h2bf, ln_g, ln_b, (void*)out, 0);
}